// Round 5
// baseline (781.381 us; speedup 1.0000x reference)
//
#include <hip/hip_runtime.h>
#include <math.h>

// Problem constants (fixed by setup_inputs)
constexpr int B_   = 8;
constexpr int CIN  = 64;     // dim
constexpr int C3   = 192;    // 3*dim
constexpr int HWID = 256;
constexpr long long NPIX = 65536; // 256*256

// k3 partial-reduction geometry (256-px chunks, LDS-staged)
constexpr int K3_CHUNKS = 256;   // 256 pixels per chunk
constexpr int K3_CELLS  = 1088;  // 1024 gram + 32 qn + 32 kn

// Per-batch buffer sizes (floats)
constexpr size_t SZ_QKV1_1B = (size_t)C3 * NPIX;   // 12.58M  (one batch, 192ch)
constexpr size_t SZ_QKB_1B  = (size_t)128 * NPIX;  //  8.39M  (one batch, q+k)
constexpr size_t SZ_GRAM = (size_t)B_ * 2 * 32 * 32;
constexpr size_t SZ_NORM = (size_t)B_ * 2 * 64;
constexpr size_t SZ_M    = (size_t)B_ * 64 * 64;
constexpr size_t SZ_PART = (size_t)B_ * 2 * K3_CHUNKS * K3_CELLS;

// LDS tile stride for the GEMM kernels
constexpr int LSTR = 68;

// ---------------------------------------------------------------------------
// K1: qkv1 = W_qkv (192x64) @ x_b (64xN).  LDS-tiled GEMM, thread = 4x4 tile.
// grid (1024, 3 oc-tiles, nb local batches).  Writes qkv1[lb].
// ---------------------------------------------------------------------------
__global__ __launch_bounds__(256) void k1_qkv1x1(const float* __restrict__ x,
                                                 const float* __restrict__ wqkv,
                                                 float* __restrict__ qkv1, int b0) {
  __shared__ __align__(16) float xs[64][LSTR];   // [ic][pix]
  __shared__ __align__(16) float Wt[64][LSTR];   // [ic][oc]  (transposed W)
  const int t = threadIdx.x;
  const int lb = blockIdx.z;
  const long long n0 = (long long)blockIdx.x * 64;
  const int oc0 = blockIdx.y * 64;
  const float* xb = x + (size_t)(b0 + lb) * CIN * NPIX;
  float* outb = qkv1 + (size_t)lb * SZ_QKV1_1B;

  {
    const int p4 = (t & 15) * 4;
#pragma unroll
    for (int r = 0; r < 4; ++r) {
      const int ic = (t >> 4) + 16 * r;
      const float4 v = *(const float4*)(xb + (size_t)ic * NPIX + n0 + p4);
      *(float4*)(&xs[ic][p4]) = v;
    }
    const int ic4 = (t & 15) * 4;
#pragma unroll
    for (int r = 0; r < 4; ++r) {
      const int ocl = (t >> 4) + 16 * r;
      const float4 w = *(const float4*)(wqkv + (size_t)(oc0 + ocl) * 64 + ic4);
      Wt[ic4 + 0][ocl] = w.x;
      Wt[ic4 + 1][ocl] = w.y;
      Wt[ic4 + 2][ocl] = w.z;
      Wt[ic4 + 3][ocl] = w.w;
    }
  }
  __syncthreads();

  const int ocl0 = (t >> 4) * 4;
  const int p0   = (t & 15) * 4;
  float acc[4][4] = {};
#pragma unroll 4
  for (int j = 0; j < 64; ++j) {
    const float4 a  = *(const float4*)(&Wt[j][ocl0]);
    const float4 bq = *(const float4*)(&xs[j][p0]);
    const float av[4] = {a.x, a.y, a.z, a.w};
    const float bv[4] = {bq.x, bq.y, bq.z, bq.w};
#pragma unroll
    for (int i = 0; i < 4; ++i)
#pragma unroll
      for (int p = 0; p < 4; ++p)
        acc[i][p] = fmaf(av[i], bv[p], acc[i][p]);
  }
#pragma unroll
  for (int i = 0; i < 4; ++i) {
    float4 o;
    o.x = acc[i][0]; o.y = acc[i][1]; o.z = acc[i][2]; o.w = acc[i][3];
    *(float4*)(outb + (size_t)(oc0 + ocl0 + i) * NPIX + n0 + p0) = o;
  }
}

// ---------------------------------------------------------------------------
// K2: depthwise 3x3 pad 1.  16 output rows/block (stage 18 rows), rolling
// 3-row register window.  grid (16, 192, nb).
// ---------------------------------------------------------------------------
__global__ __launch_bounds__(256) void k2_dwconv(const float* __restrict__ qkv1,
                                                 const float* __restrict__ wdw,
                                                 float* __restrict__ qkb,
                                                 size_t qkb_stride,
                                                 float* __restrict__ vout) {
  const int r0 = blockIdx.x * 16;
  const int ch = blockIdx.y;
  const int lb = blockIdx.z;
  const int t  = threadIdx.x;
  __shared__ __align__(16) float sm[18][256];
  const float* p = qkv1 + (size_t)lb * SZ_QKV1_1B + (size_t)ch * NPIX;

  for (int idx = t; idx < 18 * 64; idx += 256) {
    const int rr = idx >> 6;
    const int c4 = (idx & 63) * 4;
    const int gr = r0 - 1 + rr;
    float4 v = make_float4(0.f, 0.f, 0.f, 0.f);
    if (gr >= 0 && gr < HWID) v = *(const float4*)(p + (size_t)gr * HWID + c4);
    *(float4*)(&sm[rr][c4]) = v;
  }
  float w[9];
#pragma unroll
  for (int i = 0; i < 9; ++i) w[i] = wdw[ch * 9 + i];
  __syncthreads();

  const int col = t;
  const bool cl = (col > 0), cr = (col < 255);
  float l0 = cl ? sm[0][col - 1] : 0.f, m0 = sm[0][col], r0v = cr ? sm[0][col + 1] : 0.f;
  float l1 = cl ? sm[1][col - 1] : 0.f, m1 = sm[1][col], r1v = cr ? sm[1][col + 1] : 0.f;
  float* dst = (ch < 128)
                   ? (qkb + (size_t)lb * qkb_stride + (size_t)ch * NPIX)
                   : (vout + (size_t)lb * 64 * NPIX + (size_t)(ch - 128) * NPIX);
#pragma unroll
  for (int k = 0; k < 16; ++k) {
    const float l2 = cl ? sm[k + 2][col - 1] : 0.f;
    const float m2 = sm[k + 2][col];
    const float r2v = cr ? sm[k + 2][col + 1] : 0.f;
    float acc = w[0] * l0;
    acc = fmaf(w[1], m0, acc);  acc = fmaf(w[2], r0v, acc);
    acc = fmaf(w[3], l1, acc);  acc = fmaf(w[4], m1, acc);
    acc = fmaf(w[5], r1v, acc); acc = fmaf(w[6], l2, acc);
    acc = fmaf(w[7], m2, acc);  acc = fmaf(w[8], r2v, acc);
    dst[(size_t)(r0 + k) * HWID + col] = acc;
    l0 = l1; m0 = m1; r0v = r1v;
    l1 = l2; m1 = m2; r1v = r2v;
  }
}

// ---------------------------------------------------------------------------
// K3: Gram partials.  LDS-staged (66.5 KB -> 2 blocks/CU).  R5 fixes:
//  (a) __launch_bounds__(256, 2): per-thread demand is ~170 VGPR (acc 64 +
//      qv/kv 64 + norms/addr); the default heuristic capped at 88 and
//      SPILLED the inner loop (R4: WRITE_SIZE 139 MB of scratch, 173 us).
//      2 waves/SIMD is all LDS allows anyway, so a 256-VGPR budget is free.
//  (b) part layout back to [bh][chunk][cell]: block writes one contiguous
//      4.4 KB region (R4's [cell][chunk] scatter caused 16x partial-line
//      RMW amplification across non-coherent XCD L2s).
// grid (256, 2, nb).
// ---------------------------------------------------------------------------
__global__ __launch_bounds__(256, 2) void k3_gram(const float* __restrict__ qkbuf,
                                                  size_t qkb_stride,
                                                  float* __restrict__ part, int b0) {
  constexpr int LS = 260;   // LDS row stride (floats), 16B-aligned rows
  __shared__ __align__(16) float qs[32][LS];
  __shared__ __align__(16) float ks[32][LS];
  const int chunk = blockIdx.x;   // 0..255, 256 pixels each
  const int h = blockIdx.y;       // 0..1
  const int lb = blockIdx.z;
  const int b = b0 + lb;
  const int t = threadIdx.x;      // 0..255
  const float* base = qkbuf + (size_t)lb * qkb_stride;
  const float* qg = base + (size_t)(h * 32) * NPIX + (size_t)chunk * 256;
  const float* kg = base + (size_t)(64 + h * 32) * NPIX + (size_t)chunk * 256;

  // stage q,k tiles: 32 rows x 256 floats each, coalesced float4
  {
    const int col4 = (t & 63) * 4;
    const int rb = t >> 6;          // 0..3
#pragma unroll
    for (int it = 0; it < 8; ++it) {
      const int row = it * 4 + rb;
      *(float4*)(&qs[row][col4]) = *(const float4*)(qg + (size_t)row * NPIX + col4);
      *(float4*)(&ks[row][col4]) = *(const float4*)(kg + (size_t)row * NPIX + col4);
    }
  }
  __syncthreads();

  const int nt = t & 15;          // n-lane within 16-group
  const int tile = t >> 4;        // 0..15
  const int c0 = (tile & 3) * 8;
  const int d0 = (tile >> 2) * 8;
  const bool do_qn = (d0 == 0);   // tiles 0..3 cover all c
  const bool do_kn = (c0 == 0);   // tiles 0,4,8,12 cover all d

  float acc[8][8] = {};
  float qn[8] = {}, kn[8] = {};
#pragma unroll 1
  for (int s = 0; s < 4; ++s) {
    const int nn = s * 64 + nt * 4;
    float4 qv[8], kv[8];
#pragma unroll
    for (int i = 0; i < 8; ++i) qv[i] = *(const float4*)(&qs[c0 + i][nn]);
#pragma unroll
    for (int j = 0; j < 8; ++j) kv[j] = *(const float4*)(&ks[d0 + j][nn]);
#pragma unroll
    for (int i = 0; i < 8; ++i)
#pragma unroll
      for (int j = 0; j < 8; ++j) {
        float a = acc[i][j];
        a = fmaf(qv[i].x, kv[j].x, a);
        a = fmaf(qv[i].y, kv[j].y, a);
        a = fmaf(qv[i].z, kv[j].z, a);
        a = fmaf(qv[i].w, kv[j].w, a);
        acc[i][j] = a;
      }
    if (do_qn) {
#pragma unroll
      for (int i = 0; i < 8; ++i) {
        float a = qn[i];
        a = fmaf(qv[i].x, qv[i].x, a);
        a = fmaf(qv[i].y, qv[i].y, a);
        a = fmaf(qv[i].z, qv[i].z, a);
        a = fmaf(qv[i].w, qv[i].w, a);
        qn[i] = a;
      }
    }
    if (do_kn) {
#pragma unroll
      for (int j = 0; j < 8; ++j) {
        float a = kn[j];
        a = fmaf(kv[j].x, kv[j].x, a);
        a = fmaf(kv[j].y, kv[j].y, a);
        a = fmaf(kv[j].z, kv[j].z, a);
        a = fmaf(kv[j].w, kv[j].w, a);
        kn[j] = a;
      }
    }
  }

  // reduce over the 16 n-lanes; part layout [bh][chunk][cell] (contiguous)
  float* pb = part + (((size_t)(b * 2 + h) * K3_CHUNKS) + chunk) * K3_CELLS;
#pragma unroll
  for (int i = 0; i < 8; ++i)
#pragma unroll
    for (int j = 0; j < 8; ++j) {
      float v = acc[i][j];
      v += __shfl_xor(v, 1); v += __shfl_xor(v, 2);
      v += __shfl_xor(v, 4); v += __shfl_xor(v, 8);
      if (nt == 0) pb[(c0 + i) * 32 + (d0 + j)] = v;
    }
  if (do_qn) {
#pragma unroll
    for (int i = 0; i < 8; ++i) {
      float v = qn[i];
      v += __shfl_xor(v, 1); v += __shfl_xor(v, 2);
      v += __shfl_xor(v, 4); v += __shfl_xor(v, 8);
      if (nt == 0) pb[1024 + c0 + i] = v;
    }
  }
  if (do_kn) {
#pragma unroll
    for (int j = 0; j < 8; ++j) {
      float v = kn[j];
      v += __shfl_xor(v, 1); v += __shfl_xor(v, 2);
      v += __shfl_xor(v, 4); v += __shfl_xor(v, 8);
      if (nt == 0) pb[1056 + d0 + j] = v;
    }
  }
}

// ---------------------------------------------------------------------------
// K3R: sum chunk partials -> gram/norms, all batches.  grid 68 x 256.
// Thread = cell; reads coalesced across threads at each chunk step.
// ---------------------------------------------------------------------------
__global__ __launch_bounds__(256) void k3_reduce(const float* __restrict__ part,
                                                 float* __restrict__ gram,
                                                 float* __restrict__ norms) {
  const int e = blockIdx.x * 256 + threadIdx.x;   // 0..17407
  const int bh = e / K3_CELLS;                    // 0..15
  const int cell = e - bh * K3_CELLS;
  const float* p = part + ((size_t)bh * K3_CHUNKS) * K3_CELLS + cell;
  float s0 = 0.f, s1 = 0.f;
#pragma unroll 4
  for (int ch = 0; ch < K3_CHUNKS; ch += 2) {
    s0 += p[(size_t)ch * K3_CELLS];
    s1 += p[(size_t)(ch + 1) * K3_CELLS];
  }
  const float s = s0 + s1;
  if (cell < 1024) gram[(size_t)bh * 1024 + cell] = s;
  else             norms[(size_t)bh * 64 + (cell - 1024)] = s;
}

// ---------------------------------------------------------------------------
// K4: normalize gram -> attn; rank-based top-k (16,21,24) masked softmaxes;
// fold with W_proj -> M (64x64).  (unchanged)
// ---------------------------------------------------------------------------
__global__ __launch_bounds__(256) void k4_attn(const float* __restrict__ gram,
                                               const float* __restrict__ norms,
                                               const float* __restrict__ temp,
                                               const float* __restrict__ a1,
                                               const float* __restrict__ a2,
                                               const float* __restrict__ a3,
                                               const float* __restrict__ wproj,
                                               float* __restrict__ M) {
  const int b = blockIdx.x;
  const int t = threadIdx.x;
  __shared__ float A[2][32][32];
  if (t < 64) {
    const int h = t >> 5, c = t & 31;
    const float* g = gram + (((size_t)b * 2 + h) * 32 + c) * 32;
    const float* nb = norms + ((size_t)b * 2 + h) * 64;
    const float qn = fmaxf(sqrtf(nb[c]), 1e-12f);
    const float tmph = temp[h];
    float v[32];
#pragma unroll
    for (int d = 0; d < 32; ++d) {
      const float kn = fmaxf(sqrtf(nb[32 + d]), 1e-12f);
      v[d] = g[d] / (qn * kn) * tmph;
    }
    int rank[32];
#pragma unroll
    for (int i = 0; i < 32; ++i) {
      int r = 0;
#pragma unroll
      for (int j = 0; j < 32; ++j)
        r += (v[j] > v[i]) || (v[j] == v[i] && j < i);
      rank[i] = r;
    }
    float acc[32];
#pragma unroll
    for (int d = 0; d < 32; ++d) acc[d] = 0.f;
    const float aws[3] = {a1[0], a2[0], a3[0]};
    const int kvs[3] = {16, 21, 24};  // C/2, 2C/3, 3C/4 for C=32
#pragma unroll 1
    for (int kk = 0; kk < 3; ++kk) {
      float mx = -3.4e38f;
#pragma unroll
      for (int d = 0; d < 32; ++d)
        if (rank[d] < kvs[kk]) mx = fmaxf(mx, v[d]);
      float s = 0.f;
#pragma unroll
      for (int d = 0; d < 32; ++d)
        if (rank[d] < kvs[kk]) s += expf(v[d] - mx);
      const float inv = aws[kk] / s;
#pragma unroll
      for (int d = 0; d < 32; ++d)
        if (rank[d] < kvs[kk]) acc[d] += expf(v[d] - mx) * inv;
    }
#pragma unroll
    for (int d = 0; d < 32; ++d) A[h][c][d] = acc[d];
  }
  __syncthreads();
  for (int e = t; e < 4096; e += 256) {
    const int oc = e >> 6, j = e & 63, h = j >> 5, d = j & 31;
    float s = 0.f;
#pragma unroll
    for (int c = 0; c < 32; ++c)
      s += wproj[oc * 64 + h * 32 + c] * A[h][c][d];
    M[(size_t)b * 4096 + e] = s;
  }
}

// ---------------------------------------------------------------------------
// K5: y[b] = M[b] (64x64) @ v[b] (64xN), IN PLACE on d_out.  LDS-tiled GEMM.
// grid (1024, 8).
// ---------------------------------------------------------------------------
__global__ __launch_bounds__(256) void k5_out(float* vy,
                                              const float* __restrict__ M) {
  __shared__ __align__(16) float vs[64][LSTR];   // [j][pix]
  __shared__ __align__(16) float Mt[64][LSTR];   // [j][oc]
  const int t = threadIdx.x;
  const int b = blockIdx.y;
  const long long n0 = (long long)blockIdx.x * 64;
  float* vb = vy + (size_t)b * 64 * NPIX;
  const float* Mb = M + (size_t)b * 4096;

  {
    const int p4 = (t & 15) * 4;
#pragma unroll
    for (int r = 0; r < 4; ++r) {
      const int j = (t >> 4) + 16 * r;
      const float4 v = *(const float4*)(vb + (size_t)j * NPIX + n0 + p4);
      *(float4*)(&vs[j][p4]) = v;
    }
    const int j4 = (t & 15) * 4;
#pragma unroll
    for (int r = 0; r < 4; ++r) {
      const int oc = (t >> 4) + 16 * r;
      const float4 m = *(const float4*)(Mb + (size_t)oc * 64 + j4);
      Mt[j4 + 0][oc] = m.x;
      Mt[j4 + 1][oc] = m.y;
      Mt[j4 + 2][oc] = m.z;
      Mt[j4 + 3][oc] = m.w;
    }
  }
  __syncthreads();

  const int ocl0 = (t >> 4) * 4;
  const int p0   = (t & 15) * 4;
  float acc[4][4] = {};
#pragma unroll 4
  for (int j = 0; j < 64; ++j) {
    const float4 a  = *(const float4*)(&Mt[j][ocl0]);
    const float4 bq = *(const float4*)(&vs[j][p0]);
    const float av[4] = {a.x, a.y, a.z, a.w};
    const float bv[4] = {bq.x, bq.y, bq.z, bq.w};
#pragma unroll
    for (int i = 0; i < 4; ++i)
#pragma unroll
      for (int p = 0; p < 4; ++p)
        acc[i][p] = fmaf(av[i], bv[p], acc[i][p]);
  }
#pragma unroll
  for (int i = 0; i < 4; ++i) {
    float4 o;
    o.x = acc[i][0]; o.y = acc[i][1]; o.z = acc[i][2]; o.w = acc[i][3];
    *(float4*)(vb + (size_t)(ocl0 + i) * NPIX + n0 + p0) = o;
  }
}

extern "C" void kernel_launch(void* const* d_in, const int* in_sizes, int n_in,
                              void* d_out, int out_size, void* d_ws, size_t ws_size,
                              hipStream_t stream) {
  const float* x     = (const float*)d_in[0];
  const float* wqkv  = (const float*)d_in[1];
  const float* wdw   = (const float*)d_in[2];
  const float* wproj = (const float*)d_in[3];
  const float* temp  = (const float*)d_in[4];
  const float* a1    = (const float*)d_in[5];
  const float* a2    = (const float*)d_in[6];
  const float* a3    = (const float*)d_in[7];
  float* y = (float*)d_out;
  float* ws = (float*)d_ws;

  const size_t ws_floats = ws_size / sizeof(float);
  const size_t smalls = SZ_GRAM + SZ_NORM + SZ_M + SZ_PART;
  const size_t needA = 4 * SZ_QKV1_1B + (size_t)B_ * SZ_QKB_1B + smalls; // ~488 MB

  dim3 blk(256);
  if (ws_floats >= needA) {
    // ---- Tier A: two half-batches of 4 through k1/k2, single batched k3 ----
    float* qkv1  = ws;                               // [4][192][N]
    float* qkb   = qkv1 + 4 * SZ_QKV1_1B;            // [8][128][N]
    float* gram  = qkb + (size_t)B_ * SZ_QKB_1B;
    float* norms = gram + SZ_GRAM;
    float* M     = norms + SZ_NORM;
    float* part  = M + SZ_M;

    for (int half = 0; half < 2; ++half) {
      const int b0 = half * 4;
      k1_qkv1x1<<<dim3(1024, 3, 4), blk, 0, stream>>>(x, wqkv, qkv1, b0);
      k2_dwconv<<<dim3(16, C3, 4), blk, 0, stream>>>(
          qkv1, wdw, qkb + (size_t)b0 * SZ_QKB_1B, SZ_QKB_1B,
          y + (size_t)b0 * 64 * NPIX);
    }
    k3_gram<<<dim3(K3_CHUNKS, 2, B_), blk, 0, stream>>>(
        qkb, SZ_QKB_1B, part, 0);
    k3_reduce<<<dim3(68), blk, 0, stream>>>(part, gram, norms);
    k4_attn<<<dim3(B_), blk, 0, stream>>>(gram, norms, temp, a1, a2, a3, wproj, M);
    k5_out<<<dim3(1024, B_), blk, 0, stream>>>(y, M);
  } else {
    // ---- Tier B fallback: per-batch loop ----
    float* qkv1  = ws;                               // [1][192][N]
    float* qkb   = qkv1 + SZ_QKV1_1B;                // [1][128][N]
    float* gram  = qkb + SZ_QKB_1B;
    float* norms = gram + SZ_GRAM;
    float* M     = norms + SZ_NORM;
    float* part  = M + SZ_M;

    for (int b = 0; b < B_; ++b) {
      k1_qkv1x1<<<dim3(1024, 3, 1), blk, 0, stream>>>(x, wqkv, qkv1, b);
      k2_dwconv<<<dim3(16, C3, 1), blk, 0, stream>>>(
          qkv1, wdw, qkb, 0, y + (size_t)b * 64 * NPIX);
      k3_gram<<<dim3(K3_CHUNKS, 2, 1), blk, 0, stream>>>(qkb, 0, part, b);
    }
    k3_reduce<<<dim3(68), blk, 0, stream>>>(part, gram, norms);
    k4_attn<<<dim3(B_), blk, 0, stream>>>(gram, norms, temp, a1, a2, a3, wproj, M);
    k5_out<<<dim3(1024, B_), blk, 0, stream>>>(y, M);
  }
}